// Round 10
// baseline (328.787 us; speedup 1.0000x reference)
//
#include <hip/hip_runtime.h>

// WindowAttention: B=8, C=128, H=W=256, ws=8, heads=4, d=32, n=64 tokens/window
// r10: one block = one window, 512 thr = 8 waves; wave = (head h=wv>>1, token-half
// s=wv&1). Halves the per-wave dependency chain (96 MFMA/wave vs 192) and doubles
// waves/window. K/V halves exchanged via LDS (packed s16x4 fragments, b64 ops).
// Projections/proj: v_mfma_f32_16x16x32_bf16 (swapped-operand trick); attention:
// v_mfma_f32_16x16x16_bf16 (k-mapping == x32 C/D layout -> Q/K/V/P in registers).
// LDS 48K: [0,16K) Xt[64][128]bf16 swz(tok&15)<<4 -> Ot overlay after KV barrier;
// [16K,32K) K[h][64tok][32d] swz(tok&3)<<4; [32K,48K) V[h][32d][64tok] swz(d&7)<<4.
// __launch_bounds__(512,4): total reg budget 128/thread (arch+acc mirror costs 2x
// reported VGPR; r6/r8/r9 evidence), 2 blocks/CU = 16 waves/CU.

#define HH    256
#define WWID  256
#define SCALE 0.17677669529663687f
#define LOG2E 1.44269504088896340736f

typedef float  f32x4  __attribute__((ext_vector_type(4)));
typedef __bf16 bf16x8 __attribute__((ext_vector_type(8)));
typedef __bf16 bf16x4 __attribute__((ext_vector_type(4)));
typedef __bf16 bf16x2 __attribute__((ext_vector_type(2)));
typedef short  s16x4  __attribute__((ext_vector_type(4)));

#define K_BASE 16384
#define V_BASE 32768

__device__ __forceinline__ s16x4 pack4(f32x4 v) {
  bf16x4 b = {(__bf16)v[0], (__bf16)v[1], (__bf16)v[2], (__bf16)v[3]};
  return __builtin_bit_cast(s16x4, b);
}

#if __has_builtin(__builtin_amdgcn_mfma_f32_16x16x16bf16_1k)
__device__ __forceinline__ f32x4 mfma16(s16x4 a, s16x4 b, f32x4 c) {
  return __builtin_amdgcn_mfma_f32_16x16x16bf16_1k(a, b, c, 0, 0, 0);
}
#else
__device__ __forceinline__ f32x4 mfma16(s16x4 a, s16x4 b, f32x4 c) {
  asm("v_mfma_f32_16x16x16_bf16 %0, %1, %2, %0" : "+v"(c) : "v"(a), "v"(b));
  return c;
}
#endif

__global__ void prep_weights(const float* __restrict__ wqkv,
                             const float* __restrict__ wproj,
                             __bf16* __restrict__ wbf) {
  int i = blockIdx.x * 256 + threadIdx.x;          // 65536 total
  float v = (i < 49152) ? wqkv[i] : wproj[i - 49152];
  if (i < 16384) v *= SCALE * LOG2E;               // fold softmax scale + log2e into Wq
  wbf[i] = (__bf16)v;
}

__global__ __launch_bounds__(512, 4)
void winattn_main(const float* __restrict__ x,
                  const __bf16* __restrict__ wqkv,   // [384][128] bf16 (Q rows pre-scaled)
                  const __bf16* __restrict__ wproj,  // [128][128] bf16
                  const float* __restrict__ bproj,
                  float* __restrict__ out) {
  __shared__ __align__(16) char smem[49152];

  const int tid  = threadIdx.x;
  const int lane = tid & 63;
  const int wv   = tid >> 6;       // 0..7
  const int h    = wv >> 1;        // head
  const int s    = wv & 1;         // token-half (q rows s*32..s*32+31, K/V-producer half)
  const int l15  = lane & 15;
  const int l4   = lane >> 4;

  // XCD-aware swizzle: XCD k owns batch k.
  const int bid = blockIdx.x;
  const int win = ((bid & 7) << 10) | (bid >> 3);
  const int b   = win >> 10;
  const int wy  = (win >> 5) & 31;
  const int wx  = win & 31;
  const int gy0 = wy * 8, gx0 = wx * 8;

  // ---------------- Phase A: load window -> Xt[tok][c] bf16 (swz &15) ----------------
  #pragma unroll
  for (int it = 0; it < 2; ++it) {
    int idx   = tid + it * 512;        // 1024 tasks: (cpair 64) x (ty 8) x (tx4 2)
    int cpair = idx >> 4;
    int r     = idx & 15;
    int ty    = r >> 1, tx4 = r & 1;
    const float* px = x + (((size_t)(b * 128 + 2 * cpair) * HH + gy0 + ty) * WWID + gx0 + tx4 * 4);
    float4 v0 = *(const float4*)px;
    float4 v1 = *(const float4*)(px + (size_t)HH * WWID);
    float a0[4] = {v0.x, v0.y, v0.z, v0.w};
    float a1[4] = {v1.x, v1.y, v1.z, v1.w};
    #pragma unroll
    for (int i = 0; i < 4; ++i) {
      int tok = ty * 8 + tx4 * 4 + i;
      bf16x2 w2 = {(__bf16)a0[i], (__bf16)a1[i]};
      int byte = (tok * 256 + cpair * 4) ^ ((tok & 15) << 4);
      *(bf16x2*)(smem + byte) = w2;
    }
  }
  __syncthreads();

  // Xt (later Ot) fragment; A/B operand lane mappings are identical.
  #define XT_AFRAG(mt, kt) \
    (*(const bf16x8*)(smem + ((((mt) * 16 + l15) * 256 + ((kt) * 32 + l4 * 8) * 2) ^ \
                              ((((mt) * 16 + l15) & 15) << 4))))

  // ---------------- Q pass (swapped; q-half s only): lane=tok, regs=d ----------------
  s16x4 qb[2][2];   // [nt2][tq]
  {
    f32x4 acc[2][2] = {};
    #pragma unroll
    for (int kt = 0; kt < 4; ++kt) {
      bf16x8 xf[2];
      #pragma unroll
      for (int mq = 0; mq < 2; ++mq) xf[mq] = XT_AFRAG(s * 2 + mq, kt);
      #pragma unroll
      for (int nt2 = 0; nt2 < 2; ++nt2) {
        bf16x8 w = *(const bf16x8*)(wqkv + (size_t)(h * 32 + nt2 * 16 + l15) * 128 + kt * 32 + l4 * 8);
        #pragma unroll
        for (int mq = 0; mq < 2; ++mq)
          acc[nt2][mq] = __builtin_amdgcn_mfma_f32_16x16x32_bf16(w, xf[mq], acc[nt2][mq], 0, 0, 0);
      }
    }
    #pragma unroll
    for (int nt2 = 0; nt2 < 2; ++nt2)
      #pragma unroll
      for (int mq = 0; mq < 2; ++mq) qb[nt2][mq] = pack4(acc[nt2][mq]);
  }

  // ---------------- K pass (swapped; token-half s) -> LDS K[h][tok][d] ----------------
  {
    f32x4 acc[2][2] = {};
    #pragma unroll
    for (int kt = 0; kt < 4; ++kt) {
      bf16x8 xf[2];
      #pragma unroll
      for (int mk = 0; mk < 2; ++mk) xf[mk] = XT_AFRAG(s * 2 + mk, kt);
      #pragma unroll
      for (int nt2 = 0; nt2 < 2; ++nt2) {
        bf16x8 w = *(const bf16x8*)(wqkv + (size_t)(128 + h * 32 + nt2 * 16 + l15) * 128 + kt * 32 + l4 * 8);
        #pragma unroll
        for (int mk = 0; mk < 2; ++mk)
          acc[nt2][mk] = __builtin_amdgcn_mfma_f32_16x16x32_bf16(w, xf[mk], acc[nt2][mk], 0, 0, 0);
      }
    }
    #pragma unroll
    for (int nt2 = 0; nt2 < 2; ++nt2)
      #pragma unroll
      for (int mk = 0; mk < 2; ++mk) {
        int tok = (s * 2 + mk) * 16 + l15;     // lane = token
        int d0  = nt2 * 16 + l4 * 4;
        int byte = K_BASE + h * 4096 + ((tok * 64 + d0 * 2) ^ ((tok & 3) << 4));
        *(s16x4*)(smem + byte) = pack4(acc[nt2][mk]);
      }
  }

  // ---------------- V pass (non-swapped; token-half s) -> LDS V[h][d][tok] ----------------
  {
    f32x4 acc[2][2] = {};
    #pragma unroll
    for (int kt = 0; kt < 4; ++kt) {
      bf16x8 xf[2];
      #pragma unroll
      for (int mv = 0; mv < 2; ++mv) xf[mv] = XT_AFRAG(s * 2 + mv, kt);
      #pragma unroll
      for (int nt2 = 0; nt2 < 2; ++nt2) {
        bf16x8 w = *(const bf16x8*)(wqkv + (size_t)(256 + h * 32 + nt2 * 16 + l15) * 128 + kt * 32 + l4 * 8);
        #pragma unroll
        for (int mv = 0; mv < 2; ++mv)
          acc[nt2][mv] = __builtin_amdgcn_mfma_f32_16x16x32_bf16(xf[mv], w, acc[nt2][mv], 0, 0, 0);
      }
    }
    #pragma unroll
    for (int nt2 = 0; nt2 < 2; ++nt2)
      #pragma unroll
      for (int mv = 0; mv < 2; ++mv) {
        int d    = nt2 * 16 + l15;             // lane = d
        int tok0 = (s * 2 + mv) * 16 + l4 * 4; // regs = 4 consecutive toks
        int byte = V_BASE + h * 4096 + ((d * 128 + tok0 * 2) ^ ((d & 7) << 4));
        *(s16x4*)(smem + byte) = pack4(acc[nt2][mv]);
      }
  }
  __syncthreads();   // K/V halves complete; Xt reads done by all waves

  // ---------------- load full K/V fragments from LDS ----------------
  s16x4 kb[2][4], vb[2][4];
  #pragma unroll
  for (int nt2 = 0; nt2 < 2; ++nt2)
    #pragma unroll
    for (int m = 0; m < 4; ++m) {
      int tok = m * 16 + l15, d0 = nt2 * 16 + l4 * 4;
      kb[nt2][m] = *(const s16x4*)(smem + K_BASE + h * 4096 + ((tok * 64 + d0 * 2) ^ ((tok & 3) << 4)));
      int d = nt2 * 16 + l15, tok0 = m * 16 + l4 * 4;
      vb[nt2][m] = *(const s16x4*)(smem + V_BASE + h * 4096 + ((d * 128 + tok0 * 2) ^ ((d & 7) << 4)));
    }

  // ---------------- attention: 2 q-tiles, softmax lane-local, Ot overlays Xt ----------------
  #pragma unroll
  for (int t = 0; t < 2; ++t) {
    f32x4 st[4];
    #pragma unroll
    for (int m = 0; m < 4; ++m) {
      f32x4 z = {0.f, 0.f, 0.f, 0.f};
      st[m] = mfma16(kb[0][m], qb[0][t], z);
      st[m] = mfma16(kb[1][m], qb[1][t], st[m]);
    }
    float mx = st[0][0];
    #pragma unroll
    for (int m = 0; m < 4; ++m)
      #pragma unroll
      for (int r = 0; r < 4; ++r) mx = fmaxf(mx, st[m][r]);
    mx = fmaxf(mx, __shfl_xor(mx, 16));
    mx = fmaxf(mx, __shfl_xor(mx, 32));
    float p[4][4];
    float sm = 0.f;
    #pragma unroll
    for (int m = 0; m < 4; ++m)
      #pragma unroll
      for (int r = 0; r < 4; ++r) {
        p[m][r] = __builtin_amdgcn_exp2f(st[m][r] - mx);
        sm += p[m][r];
      }
    sm += __shfl_xor(sm, 16);
    sm += __shfl_xor(sm, 32);
    float inv = __builtin_amdgcn_rcpf(sm);
    s16x4 ap[4];
    #pragma unroll
    for (int m = 0; m < 4; ++m) {
      f32x4 pn = {p[m][0] * inv, p[m][1] * inv, p[m][2] * inv, p[m][3] * inv};
      ap[m] = pack4(pn);
    }
    f32x4 o0 = {0.f, 0.f, 0.f, 0.f}, o1 = {0.f, 0.f, 0.f, 0.f};
    #pragma unroll
    for (int m = 0; m < 4; ++m) {
      o0 = mfma16(ap[m], vb[0][m], o0);
      o1 = mfma16(ap[m], vb[1][m], o1);
    }
    // lane l15 = d, reg r = q; write Ot[64 tok][128 c] over Xt region
    #pragma unroll
    for (int r = 0; r < 4; ++r) {
      int tok = s * 32 + t * 16 + l4 * 4 + r;
      int c0  = h * 32 + l15;
      int sw  = (tok & 15) << 4;
      *(__bf16*)(smem + ((tok * 256 + c0 * 2) ^ sw))        = (__bf16)o0[r];
      *(__bf16*)(smem + ((tok * 256 + (c0 + 16) * 2) ^ sw)) = (__bf16)o1[r];
    }
  }
  __syncthreads();   // Ot complete

  // ---------------- proj GEMM: each wave owns 16 output channels ----------------
  f32x4 pacc[4] = {};  // [tok-tile]
  #pragma unroll
  for (int kt = 0; kt < 4; ++kt) {
    bf16x8 of[4];
    #pragma unroll
    for (int mt = 0; mt < 4; ++mt) of[mt] = XT_AFRAG(mt, kt);   // Ot content
    bf16x8 wp = *(const bf16x8*)(wproj + (size_t)(wv * 16 + l15) * 128 + kt * 32 + l4 * 8);
    #pragma unroll
    for (int mt = 0; mt < 4; ++mt)
      pacc[mt] = __builtin_amdgcn_mfma_f32_16x16x32_bf16(of[mt], wp, pacc[mt], 0, 0, 0);
  }

  // ---------------- direct float4 writeout + bias ----------------
  {
    int o = wv * 16 + l15;
    float bias = bproj[o];
    float* obase = out + (size_t)(b * 128 + o) * ((size_t)HH * WWID) + gy0 * WWID + gx0;
    #pragma unroll
    for (int mt = 0; mt < 4; ++mt) {
      int tok0 = mt * 16 + l4 * 4;            // 4 consecutive toks within one y-row
      int ty = tok0 >> 3, tx0 = tok0 & 7;
      float4 f = {pacc[mt][0] + bias, pacc[mt][1] + bias,
                  pacc[mt][2] + bias, pacc[mt][3] + bias};
      *(float4*)(obase + ty * WWID + tx0) = f;
    }
  }
}

extern "C" void kernel_launch(void* const* d_in, const int* in_sizes, int n_in,
                              void* d_out, int out_size, void* d_ws, size_t ws_size,
                              hipStream_t stream) {
  const float* x     = (const float*)d_in[0];
  const float* wqkv  = (const float*)d_in[1];
  const float* wproj = (const float*)d_in[2];
  const float* bproj = (const float*)d_in[3];
  float* out = (float*)d_out;

  __bf16* wbf = (__bf16*)d_ws;   // 65536 bf16 = 128 KiB scratch
  prep_weights<<<256, 256, 0, stream>>>(wqkv, wproj, wbf);
  winattn_main<<<8192, 512, 0, stream>>>(x, wbf, wbf + 49152, bproj, out);
}